// Round 1
// baseline (640.399 us; speedup 1.0000x reference)
//
#include <hip/hip_runtime.h>

#define THRESH 0.5f

constexpr int N  = 8192;   // rows of fea1 / fea2
constexpr int FD = 128;    // feature dim
constexpr int WD = 64;     // embed dim (= K of similarity GEMMs)

// ---------------------------------------------------------------------------
// Kernel 1: embed = fea @ w, row-normalize -> En  (both matrices, grid.y sel)
// grid (N/32, 2), block 256 (4 waves; each wave handles 8 rows)
// ---------------------------------------------------------------------------
__global__ __launch_bounds__(256) void embed_norm(
    const float* __restrict__ fea1, const float* __restrict__ fea2,
    const float* __restrict__ w1,   const float* __restrict__ w2,
    float* __restrict__ E1n, float* __restrict__ E2n) {
  const int which = blockIdx.y;
  const float* __restrict__ fea = which ? fea2 : fea1;
  const float* __restrict__ w   = which ? w2   : w1;
  float* __restrict__ En        = which ? E2n  : E1n;

  __shared__ float wl[FD * WD];   // 32 KB, [k][c] row-major (as in global)
  __shared__ float fl[32][FD];    // 16 KB, 32 staged feature rows

  const int t    = threadIdx.x;
  const int row0 = blockIdx.x * 32;

  // stage w: 8192 floats = 2048 float4, 8 per thread, coalesced
#pragma unroll
  for (int i = 0; i < 8; ++i) {
    const int idx = (t + i * 256) * 4;
    *(float4*)&wl[idx] = *(const float4*)&w[idx];
  }
  // stage 32 fea rows: 4096 floats = 1024 float4, 4 per thread
#pragma unroll
  for (int i = 0; i < 4; ++i) {
    const int idx = t + i * 256;          // [0,1024)
    const int r = idx >> 5;               // 32 float4 per row
    const int c = (idx & 31) * 4;
    *(float4*)&fl[r][c] = *(const float4*)&fea[(size_t)(row0 + r) * FD + c];
  }
  __syncthreads();

  const int wave = t >> 6, lane = t & 63;
#pragma unroll 1
  for (int rr = 0; rr < 8; ++rr) {
    const int r = wave * 8 + rr;
    float acc = 0.f;
#pragma unroll 16
    for (int k = 0; k < FD; ++k)
      acc = fmaf(fl[r][k], wl[k * WD + lane], acc);  // fl broadcast, wl 2-way (free)
    float ss = acc * acc;
#pragma unroll
    for (int m = 32; m >= 1; m >>= 1) ss += __shfl_xor(ss, m, 64);
    const float scale = 1.f / fmaxf(sqrtf(ss), 1e-8f);
    En[(size_t)(row0 + r) * WD + lane] = acc * scale;
  }
}

// ---------------------------------------------------------------------------
// Kernel 2: plane0 = thr(E1n @ E2n^T), plane1 = thr(E1n @ E1n^T) (symmetric)
// 128x128 tile per block, K=64 fully resident in LDS, 8x8 acc per thread.
// Upper-triangle blocks (bi<=bj) also compute plane1; bi<bj mirror-writes.
// grid (64, 64), block 256
// ---------------------------------------------------------------------------
__global__ __launch_bounds__(256, 2) void sim_kernel(
    const float* __restrict__ E1, const float* __restrict__ E2,
    float* __restrict__ out) {
  __shared__ float Asm[WD][128];  // [k][m] 32 KB
  __shared__ float Bsm[WD][128];  // [k][n] 32 KB

  const int bi = blockIdx.y, bj = blockIdx.x;
  const int t  = threadIdx.x;
  const int tx = t & 15, ty = t >> 4;

  float* __restrict__ out0 = out;
  float* __restrict__ out1 = out + (size_t)N * N;

  // ---- staging helper: 128 rows x 64 k, stored transposed [k][m] ----
  auto stage = [&](float sm[WD][128], const float* __restrict__ src) {
#pragma unroll
    for (int i = 0; i < 8; ++i) {
      const int idx = t + i * 256;        // [0,2048)
      const int m = idx & 127, kq = idx >> 7;
      float4 v = *(const float4*)&src[m * WD + kq * 4];
      sm[kq * 4 + 0][m] = v.x;
      sm[kq * 4 + 1][m] = v.y;
      sm[kq * 4 + 2][m] = v.z;
      sm[kq * 4 + 3][m] = v.w;
    }
  };

  auto thr = [](float v) { return v < THRESH ? 0.f : v; };

  float acc[8][8];

  // ---- compute into acc from Asm x Bsm ----
  auto compute = [&]() {
#pragma unroll
    for (int r = 0; r < 8; ++r)
#pragma unroll
      for (int c = 0; c < 8; ++c) acc[r][c] = 0.f;
#pragma unroll 2
    for (int k = 0; k < WD; ++k) {
      const float4 a0 = *(const float4*)&Asm[k][ty * 4];
      const float4 a1 = *(const float4*)&Asm[k][64 + ty * 4];
      const float4 b0 = *(const float4*)&Bsm[k][tx * 4];
      const float4 b1 = *(const float4*)&Bsm[k][64 + tx * 4];
      const float av[8] = {a0.x, a0.y, a0.z, a0.w, a1.x, a1.y, a1.z, a1.w};
      const float bv[8] = {b0.x, b0.y, b0.z, b0.w, b1.x, b1.y, b1.z, b1.w};
#pragma unroll
      for (int r = 0; r < 8; ++r)
#pragma unroll
        for (int c = 0; c < 8; ++c)
          acc[r][c] = fmaf(av[r], bv[c], acc[r][c]);
    }
  };

  // ---- direct tile write (rows bi-side, cols bj-side) ----
  auto write_direct = [&](float* __restrict__ dst) {
#pragma unroll
    for (int r = 0; r < 8; ++r) {
      const int R = (r < 4) ? (ty * 4 + r) : (64 + ty * 4 + (r - 4));
      float* p = dst + (size_t)(bi * 128 + R) * N + bj * 128;
      float4 v0 = make_float4(thr(acc[r][0]), thr(acc[r][1]), thr(acc[r][2]), thr(acc[r][3]));
      float4 v1 = make_float4(thr(acc[r][4]), thr(acc[r][5]), thr(acc[r][6]), thr(acc[r][7]));
      *(float4*)(p + tx * 4)      = v0;
      *(float4*)(p + 64 + tx * 4) = v1;
    }
  };

  // ================= plane 0 =================
  stage(Asm, E1 + (size_t)bi * 128 * WD);
  stage(Bsm, E2 + (size_t)bj * 128 * WD);
  __syncthreads();
  compute();
  write_direct(out0);

  // ================= plane 1 (symmetric) =================
  if (bi <= bj) {
    __syncthreads();                       // all Bsm reads done
    stage(Bsm, E1 + (size_t)bj * 128 * WD);
    __syncthreads();
    compute();
    write_direct(out1);

    if (bi < bj) {
      // mirror: out1[bj*128 + C][bi*128 + R] = acc[r][c]; float4 along r (contig)
#pragma unroll
      for (int c = 0; c < 8; ++c) {
        const int C = (c < 4) ? (tx * 4 + c) : (64 + tx * 4 + (c - 4));
        float* p = out1 + (size_t)(bj * 128 + C) * N + bi * 128;
        float4 v0 = make_float4(thr(acc[0][c]), thr(acc[1][c]), thr(acc[2][c]), thr(acc[3][c]));
        float4 v1 = make_float4(thr(acc[4][c]), thr(acc[5][c]), thr(acc[6][c]), thr(acc[7][c]));
        *(float4*)(p + ty * 4)      = v0;
        *(float4*)(p + 64 + ty * 4) = v1;
      }
    }
  }
}

extern "C" void kernel_launch(void* const* d_in, const int* in_sizes, int n_in,
                              void* d_out, int out_size, void* d_ws, size_t ws_size,
                              hipStream_t stream) {
  const float* fea1 = (const float*)d_in[0];
  const float* fea2 = (const float*)d_in[1];
  const float* w1   = (const float*)d_in[2];
  const float* w2   = (const float*)d_in[3];
  float* out = (float*)d_out;

  float* E1n = (float*)d_ws;                    // [N][WD] = 2 MB
  float* E2n = E1n + (size_t)N * WD;            // [N][WD] = 2 MB

  embed_norm<<<dim3(N / 32, 2), 256, 0, stream>>>(fea1, fea2, w1, w2, E1n, E2n);
  sim_kernel<<<dim3(64, 64), 256, 0, stream>>>(E1n, E2n, out);
}